// Round 9
// baseline (164.692 us; speedup 1.0000x reference)
//
#include <hip/hip_runtime.h>
#include <cfloat>
#include <math.h>

#define N_TOK 32768
#define DIM   256
#define MCODE 1024

typedef unsigned short u16;
typedef unsigned long long u64;
typedef __attribute__((ext_vector_type(8))) _Float16 h16x8;
typedef __attribute__((ext_vector_type(4))) float f32x4;

constexpr float DECAY_ = 0.999f;
constexpr float OMD_   = (float)(1.0 - 0.999);   // match jax double->f32 promotion
constexpr float EPS_   = 1e-5f;
constexpr float MEPS_  = (float)(1024 * 1e-5);   // M * EPS in double, then f32

// ---- workspace layout (float offsets) ----
// MUST stay <= 3,284,992 B (Round-1-proven ws_size bound).
constexpr int WS_EH   = 0;        // eh[1024*256] fp16 (fragment order) -> 131072 floats
constexpr int WS_ESQ  = 262144;   // esq[1024]
constexpr int WS_CNTI = 263168;   // int counts[1024] (zeroed in setup)
constexpr int WS_BI   = 264192;   // int bi[32768]
constexpr int WS_LP   = 296960;   // loss partials[2048]
constexpr int WS_KEY  = 299008;   // u64 keys[32768] (8B-aligned)

// ---- output layout (float offsets) ----
constexpr int OUT_Q        = 0;
constexpr int OUT_COMMIT   = 8388608;
constexpr int OUT_CODEBOOK = 8388609;
constexpr int OUT_PERP     = 8388610;
constexpr int OUT_NE       = 8388611;
constexpr int OUT_NC       = 8650755;
constexpr int OUT_NW       = 8651779;

static __device__ __forceinline__ void gl2lds16(const u16* g, char* l) {
    __builtin_amdgcn_global_load_lds(
        (const __attribute__((address_space(1))) unsigned int*)g,
        (__attribute__((address_space(3))) unsigned int*)l, 16, 0, 0);
}
// monotone float->uint map: a<b  <=>  map(a)<map(b)  (finite floats)
static __device__ __forceinline__ unsigned fmap(float f) {
    unsigned u = __float_as_uint(f);
    return (u & 0x80000000u) ? ~u : (u | 0x80000000u);
}

// MFMA-fragment global order (for the small e-pack only):
// dst[wave*512 + lane*8 + j] <-> src[row=(wave>>6)*128+(wave&7)*16+(lane&15)]
//                                   [k=((wave>>3)&7)*32+(lane>>4)*8+j]
static __device__ __forceinline__ void pack_wave_h16(const float* __restrict__ src,
                                                     u16* __restrict__ dst,
                                                     int wave_id, int lane,
                                                     float scale) {
    int rb = wave_id >> 6, kc = (wave_id >> 3) & 7, t = wave_id & 7;
    int row = rb * 128 + t * 16 + (lane & 15);
    int k   = kc * 32 + (lane >> 4) * 8;
    const float* s = &src[row * DIM + k];
    float4 v0 = *(const float4*)s, v1 = *(const float4*)(s + 4);
    h16x8 hv;
    hv[0]=(_Float16)(v0.x*scale); hv[1]=(_Float16)(v0.y*scale);
    hv[2]=(_Float16)(v0.z*scale); hv[3]=(_Float16)(v0.w*scale);
    hv[4]=(_Float16)(v1.x*scale); hv[5]=(_Float16)(v1.y*scale);
    hv[6]=(_Float16)(v1.z*scale); hv[7]=(_Float16)(v1.w*scale);
    *(h16x8*)&dst[(size_t)wave_id * 512 + lane * 8] = hv;
}

// R9 mini-setup: NO x-pack (scores converts x in-kernel now). 513 blocks:
// e-pack fp16*1024 (0..127), esq (128..383), keys init (384..511), cnti (512).
// e pre-scaled by 2^10 (exact pow2, keeps fp16 normal); undone exactly in
// scores' fp32 epilogue (acc/512).
__global__ __launch_bounds__(256) void vq_setup(const float* __restrict__ emb,
                                                u16* __restrict__ eh,
                                                float* __restrict__ esq,
                                                u64* __restrict__ keys,
                                                int* __restrict__ cnti) {
    const int p = blockIdx.x, tid = threadIdx.x;
    const int lane = tid & 63, w = tid >> 6;
    if (p < 128) {
        pack_wave_h16(emb, eh, p * 4 + w, lane, 1024.0f);
    } else if (p < 384) {
        int c = (p - 128) * 4 + w;
        float4 v = *(const float4*)&emb[c * DIM + lane * 4];
        float s = v.x * v.x + v.y * v.y + v.z * v.z + v.w * v.w;
#pragma unroll
        for (int off = 32; off; off >>= 1) s += __shfl_xor(s, off, 64);
        if (lane == 0) esq[c] = s;
    } else if (p < 512) {
        keys[(p - 384) * 256 + tid] = ~0ULL;
    } else {
#pragma unroll
        for (int i = 0; i < 4; ++i) cnti[i * 256 + tid] = 0;
    }
}

// main MFMA scores+argmin: 2048 blocks; XCD swizzle. block = 128x128,
// 4 waves 2x2, wave = 4x4 grid of 16x16x32 fp16 MFMA. dist = esq - acc/512.
//
// R9: A-side reads x f32 DIRECTLY (no xh array, no x-pack kernel).
// Per wave per phase: 2 A-slots via reg-staging (guide T14: 4x float4 loads
// issued at phase START, cvt+ds_write_b128 AFTER the MFMAs -> HBM latency
// hides under compute; ds_write linear = conflict-free). Conversions are the
// identical RN f32->fp16 as the old pack -> keys bit-identical. B-side stays
// R3's proven coalesced global_load_lds from the (kept) eh fragment pack.
// Double-buffered 2x16KB inside the 33792B epilogue scratch; one
// __syncthreads per phase (same barrier count as R3/R8-neutral structure).
__global__ __launch_bounds__(256) void vq_scores_mfma(const float* __restrict__ x,
                                                      const u16* __restrict__ eh,
                                                      const float* __restrict__ esq,
                                                      u64* __restrict__ keys) {
    __shared__ __align__(16) char smem[33792];   // 2 x (A 8KB | B 8KB)
    const int tid  = threadIdx.x;
    const int lane = tid & 63, w = tid >> 6;
    const int wm = w & 1, wn = w >> 1;
    const int raw = blockIdx.x;
    const int rb = (raw >> 6) * 8 + (raw & 7);
    const int cs = (raw >> 3) & 7;
    const int ln16 = lane & 15, q4 = lane >> 4;

    const u16* gb1 = eh + (size_t)cs * 32768;

    // A reg-staging sources: wave w owns slots {2w, 2w+1}; lane covers
    // x[rb*128 + slot*16 + ln16][kc*32 + q4*8 .. +8]  (8 f32 = 2 float4;
    // lanes {l,l+16,l+32,l+48} cover one row's full 128B line — full-line gather)
    const float* as0 = x + ((size_t)(rb * 128 + (2 * w)     * 16 + ln16)) * DIM + q4 * 8;
    const float* as1 = x + ((size_t)(rb * 128 + (2 * w + 1) * 16 + ln16)) * DIM + q4 * 8;

    float4 a0, a1, a2, a3;   // in-flight A fragments (named: rule-#20 safe)

    // B: wave w stages slots {2w, 2w+1} of the 8KB B chunk via glds
    auto STAGE_B = [&](int KC, char* base) {
#pragma unroll
        for (int j = 0; j < 2; ++j) {
            int slot = w * 2 + j;
            const u16* g = gb1 + KC * 4096 + slot * 512 + lane * 8;
            gl2lds16(g, base + 8192 + slot * 1024);
        }
    };
    auto LOAD_A = [&](int KC) {
        a0 = *(const float4*)(as0 + KC * 32);
        a1 = *(const float4*)(as0 + KC * 32 + 4);
        a2 = *(const float4*)(as1 + KC * 32);
        a3 = *(const float4*)(as1 + KC * 32 + 4);
    };
    auto WRITE_A = [&](char* base) {
        h16x8 h0, h1;
        h0[0]=(_Float16)a0.x; h0[1]=(_Float16)a0.y; h0[2]=(_Float16)a0.z; h0[3]=(_Float16)a0.w;
        h0[4]=(_Float16)a1.x; h0[5]=(_Float16)a1.y; h0[6]=(_Float16)a1.z; h0[7]=(_Float16)a1.w;
        h1[0]=(_Float16)a2.x; h1[1]=(_Float16)a2.y; h1[2]=(_Float16)a2.z; h1[3]=(_Float16)a2.w;
        h1[4]=(_Float16)a3.x; h1[5]=(_Float16)a3.y; h1[6]=(_Float16)a3.z; h1[7]=(_Float16)a3.w;
        *(h16x8*)(base + (2 * w)     * 1024 + lane * 16) = h0;
        *(h16x8*)(base + (2 * w + 1) * 1024 + lane * 16) = h1;
    };

    f32x4 acc[4][4];
#pragma unroll
    for (int i = 0; i < 4; ++i)
#pragma unroll
        for (int j = 0; j < 4; ++j) acc[i][j] = (f32x4)0.f;

    // prologue: chunk 0 into buf0
    STAGE_B(0, smem);
    LOAD_A(0);
    WRITE_A(smem);             // compiler waits the f32 loads before cvt
    __syncthreads();           // drains B glds + A ds_write

    for (int kc = 0; kc < 8; ++kc) {
        char* cur = smem + (kc & 1) * 16384;
        char* nxt = smem + ((kc + 1) & 1) * 16384;
        if (kc < 7) { STAGE_B(kc + 1, nxt); LOAD_A(kc + 1); }  // issue early

        const h16x8* Ah = (const h16x8*)cur;
        const h16x8* Bh = (const h16x8*)(cur + 8192);
        h16x8 ah[4];
#pragma unroll
        for (int tm = 0; tm < 4; ++tm)
            ah[tm] = Ah[(wm * 4 + tm) * 64 + lane];
#pragma unroll
        for (int tn = 0; tn < 4; ++tn) {
            h16x8 bh = Bh[(wn * 4 + tn) * 64 + lane];
#pragma unroll
            for (int tm = 0; tm < 4; ++tm) {
                acc[tm][tn] = __builtin_amdgcn_mfma_f32_16x16x32_f16(ah[tm], bh, acc[tm][tn], 0, 0, 0);
            }
        }
        if (kc < 7) WRITE_A(nxt);   // cvt + ds_write late (T14: latency hidden)
        __syncthreads();            // drains B glds + A write; WAR fence
    }

    // epilogue: dist = esq - acc/512, per-row argmin. (exact R3)
    // C/D layout: col = lane&15, row = (lane>>4)*4 + reg (m89/m91-verified)
    float* cv = (float*)smem;            // [128 rows][33 slots] pad -> conflict-free
    int*   ci = (int*)(smem + 16896);
#pragma unroll
    for (int tm = 0; tm < 4; ++tm) {
        float bv[4];
        int   bi[4];
#pragma unroll
        for (int r = 0; r < 4; ++r) { bv[r] = FLT_MAX; bi[r] = 0; }
#pragma unroll
        for (int tn = 0; tn < 4; ++tn) {          // ascending col -> lowest-idx ties
            int c = cs * 128 + wn * 64 + tn * 16 + ln16;
            float ec = esq[c];
#pragma unroll
            for (int r = 0; r < 4; ++r) {
                float d = fmaf(-0.001953125f, acc[tm][tn][r], ec);
                if (d < bv[r]) { bv[r] = d; bi[r] = c; }
            }
        }
        int row0 = wm * 64 + tm * 16 + q4 * 4;
        int slot = wn * 16 + ln16;
#pragma unroll
        for (int r = 0; r < 4; ++r) {
            cv[(row0 + r) * 33 + slot] = bv[r];
            ci[(row0 + r) * 33 + slot] = bi[r];
        }
    }
    __syncthreads();
    if (tid < 128) {
        float bv = cv[tid * 33];
        int   bi = ci[tid * 33];
#pragma unroll
        for (int s = 1; s < 32; ++s) {
            float v = cv[tid * 33 + s];
            int  ix = ci[tid * 33 + s];
            if (v < bv || (v == bv && ix < bi)) { bv = v; bi = ix; }
        }
        u64 key = ((u64)fmap(bv) << 32) | (unsigned)bi;
        atomicMin(&keys[rb * 128 + tid], key);
    }
}

// streaming quantize + straight-through + loss partials + histogram + bi array.
// 2048 blocks x 16 rows; float4 throughout; one int atomic per row. (R4-proven;
// fusion-into-mega measured 89us latency-bound — keep the split.)
__global__ __launch_bounds__(256) void vq_quant(const float* __restrict__ x,
                                                const float* __restrict__ emb,
                                                const u64* __restrict__ keys,
                                                float* __restrict__ outq,
                                                int* __restrict__ cnti,
                                                int* __restrict__ bi_arr,
                                                float* __restrict__ lpart) {
    const int tid = threadIdx.x, lane = tid & 63, w = tid >> 6;
    const float4* x4 = (const float4*)x;
    const float4* e4 = (const float4*)emb;
    float4* o4 = (float4*)outq;
    float lacc = 0.f;
#pragma unroll
    for (int it = 0; it < 4; ++it) {
        int row = blockIdx.x * 16 + it * 4 + w;
        int bi = (int)(unsigned)(keys[row] & 0xffffffffULL);
        if (lane == 0) { atomicAdd(&cnti[bi], 1); bi_arr[row] = bi; }
        float4 xv = x4[row * 64 + lane];
        float4 ev = e4[bi * 64 + lane];
        float4 q;
        q.x = xv.x + (ev.x - xv.x);  q.y = xv.y + (ev.y - xv.y);
        q.z = xv.z + (ev.z - xv.z);  q.w = xv.w + (ev.w - xv.w);
        o4[row * 64 + lane] = q;
        float dx = xv.x - ev.x, dy = xv.y - ev.y, dz = xv.z - ev.z, dwv = xv.w - ev.w;
        lacc += dx * dx + dy * dy + dz * dz + dwv * dwv;
    }
#pragma unroll
    for (int off = 32; off; off >>= 1) lacc += __shfl_xor(lacc, off, 64);
    __shared__ float red[4];
    if (lane == 0) red[w] = lacc;
    __syncthreads();
    if (tid == 0) lpart[blockIdx.x] = red[0] + red[1] + red[2] + red[3];
}

// mega-tail: grid 1024, one block per code m.
// int4 + unroll scan; n via the exact identity sum(counts) == N_TOK.
#define MEGA_CAP 6144
__global__ __launch_bounds__(256) void vq_mega(const float* __restrict__ x,
                                               const float* __restrict__ ema_count,
                                               const float* __restrict__ ema_weight,
                                               const int* __restrict__ cnti,
                                               const int* __restrict__ bi_arr,
                                               const float* __restrict__ lpart,
                                               float* __restrict__ out) {
    const int m = blockIdx.x, tid = threadIdx.x;
    __shared__ float fs[256];
    __shared__ int list[MEGA_CAP];
    __shared__ int lcount;

    float rsum = 0.f;
#pragma unroll
    for (int i = 0; i < 4; ++i) rsum += ema_count[tid * 4 + i];
    fs[tid] = rsum;
    if (tid == 0) lcount = 0;
    __syncthreads();
    for (int s = 128; s; s >>= 1) { if (tid < s) fs[tid] += fs[tid + s]; __syncthreads(); }
    const float n = DECAY_ * fs[0] + OMD_ * (float)N_TOK;
    __syncthreads();

    // scan bi_arr (int4, unrolled -> loads pipelined) for rows of code m
    const int4* b4 = (const int4*)bi_arr;
#pragma unroll 4
    for (int i = tid; i < N_TOK / 4; i += 256) {
        int4 v = b4[i];
        if (v.x == m) { int p = atomicAdd(&lcount, 1); if (p < MEGA_CAP) list[p] = 4 * i; }
        if (v.y == m) { int p = atomicAdd(&lcount, 1); if (p < MEGA_CAP) list[p] = 4 * i + 1; }
        if (v.z == m) { int p = atomicAdd(&lcount, 1); if (p < MEGA_CAP) list[p] = 4 * i + 2; }
        if (v.w == m) { int p = atomicAdd(&lcount, 1); if (p < MEGA_CAP) list[p] = 4 * i + 3; }
    }
    __syncthreads();
    const int nm = lcount;
    float dwsum;
    if (nm <= MEGA_CAP) {
        float a0 = 0.f, a1 = 0.f, a2 = 0.f, a3 = 0.f;
        int i = 0;
        for (; i + 4 <= nm; i += 4) {
            a0 += x[list[i]     * DIM + tid];
            a1 += x[list[i + 1] * DIM + tid];
            a2 += x[list[i + 2] * DIM + tid];
            a3 += x[list[i + 3] * DIM + tid];
        }
        for (; i < nm; ++i) a0 += x[list[i] * DIM + tid];
        dwsum = (a0 + a1) + (a2 + a3);
    } else {
        // defensive fallback (not expected with this data distribution)
        __shared__ int chunk[256];
        float a0 = 0.f;
        for (int base = 0; base < N_TOK; base += 256) {
            __syncthreads();
            chunk[tid] = bi_arr[base + tid];
            __syncthreads();
            for (int j = 0; j < 256; ++j)
                if (chunk[j] == m) a0 += x[(base + j) * DIM + tid];
        }
        dwsum = a0;
    }

    float raw_m = DECAY_ * ema_count[m] + OMD_ * (float)nm;
    float ncm = (raw_m + EPS_) / (n + MEPS_) * n;
    float nw = DECAY_ * ema_weight[m * DIM + tid] + OMD_ * dwsum;
    out[OUT_NW + m * DIM + tid] = nw;
    out[OUT_NE + m * DIM + tid] = nw / ncm;
    if (tid == 0) out[OUT_NC + m] = ncm;

    if (m == 0) {
        float ent = 0.f;
#pragma unroll
        for (int i = 0; i < 4; ++i) {
            float p = (float)cnti[tid * 4 + i] / (float)N_TOK;
            ent += p * logf(p + 1e-10f);
        }
        __syncthreads();
        fs[tid] = ent;
        __syncthreads();
        for (int s = 128; s; s >>= 1) { if (tid < s) fs[tid] += fs[tid + s]; __syncthreads(); }
        float entr = fs[0];
        __syncthreads();
        float ls = 0.f;
#pragma unroll
        for (int k = 0; k < 8; ++k) ls += lpart[tid + 256 * k];
        fs[tid] = ls;
        __syncthreads();
        for (int s = 128; s; s >>= 1) { if (tid < s) fs[tid] += fs[tid + s]; __syncthreads(); }
        if (tid == 0) {
            float mean = fs[0] / (float)(N_TOK * DIM);
            out[OUT_COMMIT]   = 0.25f * mean;
            out[OUT_CODEBOOK] = mean;
            out[OUT_PERP]     = expf(-entr);
        }
    }
}

extern "C" void kernel_launch(void* const* d_in, const int* in_sizes, int n_in,
                              void* d_out, int out_size, void* d_ws, size_t ws_size,
                              hipStream_t stream) {
    const float* x          = (const float*)d_in[0];
    const float* emb        = (const float*)d_in[1];
    const float* ema_count  = (const float*)d_in[2];
    const float* ema_weight = (const float*)d_in[3];
    float* out = (float*)d_out;
    float* wf  = (float*)d_ws;

    u16* eh = (u16*)(wf + WS_EH);

    float* esq    = wf + WS_ESQ;
    int*   cnti   = (int*)(wf + WS_CNTI);
    int*   bi_arr = (int*)(wf + WS_BI);
    float* lpart  = wf + WS_LP;
    u64*   keys   = (u64*)(wf + WS_KEY);

    vq_setup<<<513, 256, 0, stream>>>(emb, eh, esq, keys, cnti);
    vq_scores_mfma<<<2048, 256, 0, stream>>>(x, eh, esq, keys);
    vq_quant<<<2048, 256, 0, stream>>>(x, emb, keys, out, cnti, bi_arr, lpart);
    vq_mega<<<MCODE, 256, 0, stream>>>(x, ema_count, ema_weight, cnti, bi_arr,
                                       lpart, out);
}

// Round 10
// 159.680 us; speedup vs baseline: 1.0314x; 1.0314x over previous
//
#include <hip/hip_runtime.h>
#include <cfloat>
#include <math.h>

#define N_TOK 32768
#define DIM   256
#define MCODE 1024

typedef unsigned short u16;
typedef unsigned long long u64;
typedef __attribute__((ext_vector_type(8))) _Float16 h16x8;
typedef __attribute__((ext_vector_type(4))) float f32x4;

constexpr float DECAY_ = 0.999f;
constexpr float OMD_   = (float)(1.0 - 0.999);   // match jax double->f32 promotion
constexpr float EPS_   = 1e-5f;
constexpr float MEPS_  = (float)(1024 * 1e-5);   // M * EPS in double, then f32

// ---- workspace layout (float offsets) ----
// MUST stay <= 3,284,992 B (Round-1-proven ws_size bound).
constexpr int WS_EH   = 0;        // eh[1024*256] fp16 (fragment order) -> 131072 floats
constexpr int WS_ESQ  = 262144;   // esq[1024]
constexpr int WS_CNTI = 263168;   // int counts[1024] (zeroed in setup)
constexpr int WS_BI   = 264192;   // int bi[32768]
constexpr int WS_LP   = 296960;   // loss partials[2048]
constexpr int WS_KEY  = 299008;   // u64 keys[32768] (8B-aligned)

// ---- output layout (float offsets) ----
constexpr int OUT_Q        = 0;
constexpr int OUT_COMMIT   = 8388608;
constexpr int OUT_CODEBOOK = 8388609;
constexpr int OUT_PERP     = 8388610;
constexpr int OUT_NE       = 8388611;
constexpr int OUT_NC       = 8650755;
constexpr int OUT_NW       = 8651779;

static __device__ __forceinline__ void gl2lds16(const u16* g, char* l) {
    __builtin_amdgcn_global_load_lds(
        (const __attribute__((address_space(1))) unsigned int*)g,
        (__attribute__((address_space(3))) unsigned int*)l, 16, 0, 0);
}
// monotone float->uint map: a<b  <=>  map(a)<map(b)  (finite floats)
static __device__ __forceinline__ unsigned fmap(float f) {
    unsigned u = __float_as_uint(f);
    return (u & 0x80000000u) ? ~u : (u | 0x80000000u);
}

// MFMA-fragment global order (R3-proven; staging loads are 1KB/wave linear):
// dst[wave*512 + lane*8 + j] <-> src[row=(wave>>6)*128+(wave&7)*16+(lane&15)]
//                                   [k=((wave>>3)&7)*32+(lane>>4)*8+j]
static __device__ __forceinline__ void pack_wave_h16(const float* __restrict__ src,
                                                     u16* __restrict__ dst,
                                                     int wave_id, int lane,
                                                     float scale) {
    int rb = wave_id >> 6, kc = (wave_id >> 3) & 7, t = wave_id & 7;
    int row = rb * 128 + t * 16 + (lane & 15);
    int k   = kc * 32 + (lane >> 4) * 8;
    const float* s = &src[row * DIM + k];
    float4 v0 = *(const float4*)s, v1 = *(const float4*)(s + 4);
    h16x8 hv;
    hv[0]=(_Float16)(v0.x*scale); hv[1]=(_Float16)(v0.y*scale);
    hv[2]=(_Float16)(v0.z*scale); hv[3]=(_Float16)(v0.w*scale);
    hv[4]=(_Float16)(v1.x*scale); hv[5]=(_Float16)(v1.y*scale);
    hv[6]=(_Float16)(v1.z*scale); hv[7]=(_Float16)(v1.w*scale);
    *(h16x8*)&dst[(size_t)wave_id * 512 + lane * 8] = hv;
}

// fused setup (exact R3): pack x fp16 (blocks 0..4095), pack e fp16*1024
// (+0..127), esq (+128..383), keys init (+384..511), counts zero (+512).
// e pre-scaled by 2^10 (exact pow2, keeps fp16 normal); undone exactly in
// scores' fp32 epilogue (acc/512). R9's x-direct read in scores regressed
// (per-lane gather splits 16-ways) — the fragment-order pack stays.
__global__ __launch_bounds__(256) void vq_setup(const float* __restrict__ x,
                                                const float* __restrict__ emb,
                                                u16* __restrict__ xh,
                                                u16* __restrict__ eh,
                                                float* __restrict__ esq,
                                                u64* __restrict__ keys,
                                                int* __restrict__ cnti) {
    const int b = blockIdx.x, tid = threadIdx.x;
    const int lane = tid & 63, w = tid >> 6;
    if (b < 4096) { pack_wave_h16(x, xh, b * 4 + w, lane, 1.0f); return; }
    const int p = b - 4096;
    if (p < 128) {
        pack_wave_h16(emb, eh, p * 4 + w, lane, 1024.0f);
    } else if (p < 384) {
        int c = (p - 128) * 4 + w;
        float4 v = *(const float4*)&emb[c * DIM + lane * 4];
        float s = v.x * v.x + v.y * v.y + v.z * v.z + v.w * v.w;
#pragma unroll
        for (int off = 32; off; off >>= 1) s += __shfl_xor(s, off, 64);
        if (lane == 0) esq[c] = s;
    } else if (p < 512) {
        keys[(p - 384) * 256 + tid] = ~0ULL;
    } else {
#pragma unroll
        for (int i = 0; i < 4; ++i) cnti[i * 256 + tid] = 0;
    }
}

// main MFMA scores+argmin: 2048 blocks; XCD swizzle. block = 128x128,
// 4 waves 2x2, wave = 4x4 grid of 16x16x32 fp16 MFMA. dist = esq - acc/512.
//
// R10: exact R3 staging loop (fragment-order glds, 2-sync single-buffer —
// the only staging pattern that measured fast: R5/R6/R9 alternatives all
// regressed). NEW: register-only argmin epilogue. R9's profile showed
// Occupancy ~25% — the old [128][33] LDS scratch pushed LDS to 33792B,
// capping residency at ~2.5 blocks/CU while the loop is drain-stall-bound.
// Now: pack key=(fmap(d)<<32|col) per candidate, butterfly u64-min over
// lane bits 0-3 (ln16 axis = the 16 col-candidates of each row), lane
// ln16==0 atomicMin's keys[row]. Bit-identical keys (fmap monotone, ties ->
// lower col, same as LDS scan order). LDS 33792 -> 16384 => 8 blocks/CU
// (wave-cap) — per-phase drains of different blocks now overlap (TLP).
__global__ __launch_bounds__(256) void vq_scores_mfma(const u16* __restrict__ xh,
                                                      const u16* __restrict__ eh,
                                                      const float* __restrict__ esq,
                                                      u64* __restrict__ keys) {
    __shared__ __align__(16) char smem[16384];   // A 8KB | B 8KB (staging only)
    const int tid  = threadIdx.x;
    const int lane = tid & 63, w = tid >> 6;
    const int wm = w & 1, wn = w >> 1;
    const int raw = blockIdx.x;
    const int rb = (raw >> 6) * 8 + (raw & 7);
    const int cs = (raw >> 3) & 7;
    const int ln16 = lane & 15, quad = lane >> 4;

    const u16* gb0 = xh + (size_t)rb * 32768;
    const u16* gb1 = eh + (size_t)cs * 32768;

    const h16x8* Ah = (const h16x8*)(smem);
    const h16x8* Bh = (const h16x8*)(smem + 8192);

    f32x4 acc[4][4];
#pragma unroll
    for (int i = 0; i < 4; ++i)
#pragma unroll
        for (int j = 0; j < 4; ++j) acc[i][j] = (f32x4)0.f;

    for (int kc = 0; kc < 8; ++kc) {
        __syncthreads();   // previous chunk's frag reads done before overwrite
        // 16 x 1KB wave-loads per chunk; wave w takes flat indices [4w, 4w+4)
#pragma unroll
        for (int j = 0; j < 4; ++j) {
            int t = w * 4 + j;
            int arr = t >> 3, slot = t & 7;
            const u16* g = (arr == 0 ? gb0 : gb1)
                           + kc * 4096 + slot * 512 + lane * 8;
            gl2lds16(g, smem + arr * 8192 + slot * 1024);
        }
        __syncthreads();   // drains vmcnt (incl. global_load_lds) + barrier

        h16x8 ah[4];
#pragma unroll
        for (int tm = 0; tm < 4; ++tm)
            ah[tm] = Ah[(wm * 4 + tm) * 64 + lane];
#pragma unroll
        for (int tn = 0; tn < 4; ++tn) {
            h16x8 bh = Bh[(wn * 4 + tn) * 64 + lane];
#pragma unroll
            for (int tm = 0; tm < 4; ++tm) {
                acc[tm][tn] = __builtin_amdgcn_mfma_f32_16x16x32_f16(ah[tm], bh, acc[tm][tn], 0, 0, 0);
            }
        }
    }

    // register-only epilogue: dist = esq - acc/512; key-min over ln16 lanes.
    // C/D layout: col = lane&15, row = (lane>>4)*4 + reg (m89/m91-verified)
#pragma unroll
    for (int tm = 0; tm < 4; ++tm) {
        u64 bk0 = ~0ULL, bk1 = ~0ULL, bk2 = ~0ULL, bk3 = ~0ULL;
#pragma unroll
        for (int tn = 0; tn < 4; ++tn) {
            int c = cs * 128 + wn * 64 + tn * 16 + ln16;
            float ec = esq[c];
            u64 k0 = ((u64)fmap(fmaf(-0.001953125f, acc[tm][tn][0], ec)) << 32) | (unsigned)c;
            u64 k1 = ((u64)fmap(fmaf(-0.001953125f, acc[tm][tn][1], ec)) << 32) | (unsigned)c;
            u64 k2 = ((u64)fmap(fmaf(-0.001953125f, acc[tm][tn][2], ec)) << 32) | (unsigned)c;
            u64 k3 = ((u64)fmap(fmaf(-0.001953125f, acc[tm][tn][3], ec)) << 32) | (unsigned)c;
            if (k0 < bk0) bk0 = k0;
            if (k1 < bk1) bk1 = k1;
            if (k2 < bk2) bk2 = k2;
            if (k3 < bk3) bk3 = k3;
        }
        // butterfly min across the 16 ln16 lanes (lane bits 0..3 only)
#pragma unroll
        for (int off = 1; off <= 8; off <<= 1) {
            u64 o0 = __shfl_xor(bk0, off, 64);
            u64 o1 = __shfl_xor(bk1, off, 64);
            u64 o2 = __shfl_xor(bk2, off, 64);
            u64 o3 = __shfl_xor(bk3, off, 64);
            if (o0 < bk0) bk0 = o0;
            if (o1 < bk1) bk1 = o1;
            if (o2 < bk2) bk2 = o2;
            if (o3 < bk3) bk3 = o3;
        }
        if (ln16 == 0) {
            int row0 = rb * 128 + wm * 64 + tm * 16 + quad * 4;
            atomicMin(&keys[row0 + 0], bk0);
            atomicMin(&keys[row0 + 1], bk1);
            atomicMin(&keys[row0 + 2], bk2);
            atomicMin(&keys[row0 + 3], bk3);
        }
    }
}

// streaming quantize + straight-through + loss partials + histogram + bi array.
// 2048 blocks x 16 rows; float4 throughout; one int atomic per row. (R4-proven;
// fusion-into-mega measured 89us latency-bound — keep the split.)
__global__ __launch_bounds__(256) void vq_quant(const float* __restrict__ x,
                                                const float* __restrict__ emb,
                                                const u64* __restrict__ keys,
                                                float* __restrict__ outq,
                                                int* __restrict__ cnti,
                                                int* __restrict__ bi_arr,
                                                float* __restrict__ lpart) {
    const int tid = threadIdx.x, lane = tid & 63, w = tid >> 6;
    const float4* x4 = (const float4*)x;
    const float4* e4 = (const float4*)emb;
    float4* o4 = (float4*)outq;
    float lacc = 0.f;
#pragma unroll
    for (int it = 0; it < 4; ++it) {
        int row = blockIdx.x * 16 + it * 4 + w;
        int bi = (int)(unsigned)(keys[row] & 0xffffffffULL);
        if (lane == 0) { atomicAdd(&cnti[bi], 1); bi_arr[row] = bi; }
        float4 xv = x4[row * 64 + lane];
        float4 ev = e4[bi * 64 + lane];
        float4 q;
        q.x = xv.x + (ev.x - xv.x);  q.y = xv.y + (ev.y - xv.y);
        q.z = xv.z + (ev.z - xv.z);  q.w = xv.w + (ev.w - xv.w);
        o4[row * 64 + lane] = q;
        float dx = xv.x - ev.x, dy = xv.y - ev.y, dz = xv.z - ev.z, dwv = xv.w - ev.w;
        lacc += dx * dx + dy * dy + dz * dz + dwv * dwv;
    }
#pragma unroll
    for (int off = 32; off; off >>= 1) lacc += __shfl_xor(lacc, off, 64);
    __shared__ float red[4];
    if (lane == 0) red[w] = lacc;
    __syncthreads();
    if (tid == 0) lpart[blockIdx.x] = red[0] + red[1] + red[2] + red[3];
}

// mega-tail: grid 1024, one block per code m.
// int4 + unroll scan; n via the exact identity sum(counts) == N_TOK.
#define MEGA_CAP 6144
__global__ __launch_bounds__(256) void vq_mega(const float* __restrict__ x,
                                               const float* __restrict__ ema_count,
                                               const float* __restrict__ ema_weight,
                                               const int* __restrict__ cnti,
                                               const int* __restrict__ bi_arr,
                                               const float* __restrict__ lpart,
                                               float* __restrict__ out) {
    const int m = blockIdx.x, tid = threadIdx.x;
    __shared__ float fs[256];
    __shared__ int list[MEGA_CAP];
    __shared__ int lcount;

    float rsum = 0.f;
#pragma unroll
    for (int i = 0; i < 4; ++i) rsum += ema_count[tid * 4 + i];
    fs[tid] = rsum;
    if (tid == 0) lcount = 0;
    __syncthreads();
    for (int s = 128; s; s >>= 1) { if (tid < s) fs[tid] += fs[tid + s]; __syncthreads(); }
    const float n = DECAY_ * fs[0] + OMD_ * (float)N_TOK;
    __syncthreads();

    // scan bi_arr (int4, unrolled -> loads pipelined) for rows of code m
    const int4* b4 = (const int4*)bi_arr;
#pragma unroll 4
    for (int i = tid; i < N_TOK / 4; i += 256) {
        int4 v = b4[i];
        if (v.x == m) { int p = atomicAdd(&lcount, 1); if (p < MEGA_CAP) list[p] = 4 * i; }
        if (v.y == m) { int p = atomicAdd(&lcount, 1); if (p < MEGA_CAP) list[p] = 4 * i + 1; }
        if (v.z == m) { int p = atomicAdd(&lcount, 1); if (p < MEGA_CAP) list[p] = 4 * i + 2; }
        if (v.w == m) { int p = atomicAdd(&lcount, 1); if (p < MEGA_CAP) list[p] = 4 * i + 3; }
    }
    __syncthreads();
    const int nm = lcount;
    float dwsum;
    if (nm <= MEGA_CAP) {
        float a0 = 0.f, a1 = 0.f, a2 = 0.f, a3 = 0.f;
        int i = 0;
        for (; i + 4 <= nm; i += 4) {
            a0 += x[list[i]     * DIM + tid];
            a1 += x[list[i + 1] * DIM + tid];
            a2 += x[list[i + 2] * DIM + tid];
            a3 += x[list[i + 3] * DIM + tid];
        }
        for (; i < nm; ++i) a0 += x[list[i] * DIM + tid];
        dwsum = (a0 + a1) + (a2 + a3);
    } else {
        // defensive fallback (not expected with this data distribution)
        __shared__ int chunk[256];
        float a0 = 0.f;
        for (int base = 0; base < N_TOK; base += 256) {
            __syncthreads();
            chunk[tid] = bi_arr[base + tid];
            __syncthreads();
            for (int j = 0; j < 256; ++j)
                if (chunk[j] == m) a0 += x[(base + j) * DIM + tid];
        }
        dwsum = a0;
    }

    float raw_m = DECAY_ * ema_count[m] + OMD_ * (float)nm;
    float ncm = (raw_m + EPS_) / (n + MEPS_) * n;
    float nw = DECAY_ * ema_weight[m * DIM + tid] + OMD_ * dwsum;
    out[OUT_NW + m * DIM + tid] = nw;
    out[OUT_NE + m * DIM + tid] = nw / ncm;
    if (tid == 0) out[OUT_NC + m] = ncm;

    if (m == 0) {
        float ent = 0.f;
#pragma unroll
        for (int i = 0; i < 4; ++i) {
            float p = (float)cnti[tid * 4 + i] / (float)N_TOK;
            ent += p * logf(p + 1e-10f);
        }
        __syncthreads();
        fs[tid] = ent;
        __syncthreads();
        for (int s = 128; s; s >>= 1) { if (tid < s) fs[tid] += fs[tid + s]; __syncthreads(); }
        float entr = fs[0];
        __syncthreads();
        float ls = 0.f;
#pragma unroll
        for (int k = 0; k < 8; ++k) ls += lpart[tid + 256 * k];
        fs[tid] = ls;
        __syncthreads();
        for (int s = 128; s; s >>= 1) { if (tid < s) fs[tid] += fs[tid + s]; __syncthreads(); }
        if (tid == 0) {
            float mean = fs[0] / (float)(N_TOK * DIM);
            out[OUT_COMMIT]   = 0.25f * mean;
            out[OUT_CODEBOOK] = mean;
            out[OUT_PERP]     = expf(-entr);
        }
    }
}

extern "C" void kernel_launch(void* const* d_in, const int* in_sizes, int n_in,
                              void* d_out, int out_size, void* d_ws, size_t ws_size,
                              hipStream_t stream) {
    const float* x          = (const float*)d_in[0];
    const float* emb        = (const float*)d_in[1];
    const float* ema_count  = (const float*)d_in[2];
    const float* ema_weight = (const float*)d_in[3];
    float* out = (float*)d_out;
    float* wf  = (float*)d_ws;

    // xh lives in the d_out quantized region (16.8 of 33.5 MB); vq_quant
    // overwrites it afterwards.
    u16* xh = (u16*)d_out;
    u16* eh = (u16*)(wf + WS_EH);

    float* esq    = wf + WS_ESQ;
    int*   cnti   = (int*)(wf + WS_CNTI);
    int*   bi_arr = (int*)(wf + WS_BI);
    float* lpart  = wf + WS_LP;
    u64*   keys   = (u64*)(wf + WS_KEY);

    vq_setup<<<4609, 256, 0, stream>>>(x, emb, xh, eh, esq, keys, cnti);
    vq_scores_mfma<<<2048, 256, 0, stream>>>(xh, eh, esq, keys);
    vq_quant<<<2048, 256, 0, stream>>>(x, emb, keys, out, cnti, bi_arr, lpart);
    vq_mega<<<MCODE, 256, 0, stream>>>(x, ema_count, ema_weight, cnti, bi_arr,
                                       lpart, out);
}

// Round 11
// 150.645 us; speedup vs baseline: 1.0932x; 1.0600x over previous
//
#include <hip/hip_runtime.h>
#include <cfloat>
#include <math.h>

#define N_TOK 32768
#define DIM   256
#define MCODE 1024

typedef unsigned short u16;
typedef unsigned long long u64;
typedef __attribute__((ext_vector_type(8))) _Float16 h16x8;
typedef __attribute__((ext_vector_type(4))) float f32x4;

constexpr float DECAY_ = 0.999f;
constexpr float OMD_   = (float)(1.0 - 0.999);   // match jax double->f32 promotion
constexpr float EPS_   = 1e-5f;
constexpr float MEPS_  = (float)(1024 * 1e-5);   // M * EPS in double, then f32

// ---- workspace layout (float offsets) ----
// MUST stay <= 3,284,992 B (Round-1-proven ws_size bound).
constexpr int WS_EH   = 0;        // eh[1024*256] fp16 -> 131072 float slots
constexpr int WS_EL   = 131072;   // (unused since fp16 switch; layout kept)
constexpr int WS_ESQ  = 262144;   // esq[1024]
constexpr int WS_CNTI = 263168;   // int counts[1024] (zeroed in setup)
constexpr int WS_BI   = 264192;   // int bi[32768]
constexpr int WS_LP   = 296960;   // loss partials[2048]
constexpr int WS_KEY  = 299008;   // u64 keys[32768] (8B-aligned)

// ---- output layout (float offsets) ----
constexpr int OUT_Q        = 0;
constexpr int OUT_COMMIT   = 8388608;
constexpr int OUT_CODEBOOK = 8388609;
constexpr int OUT_PERP     = 8388610;
constexpr int OUT_NE       = 8388611;
constexpr int OUT_NC       = 8650755;
constexpr int OUT_NW       = 8651779;

static __device__ __forceinline__ void gl2lds16(const u16* g, char* l) {
    __builtin_amdgcn_global_load_lds(
        (const __attribute__((address_space(1))) unsigned int*)g,
        (__attribute__((address_space(3))) unsigned int*)l, 16, 0, 0);
}
// monotone float->uint map: a<b  <=>  map(a)<map(b)  (finite floats)
static __device__ __forceinline__ unsigned fmap(float f) {
    unsigned u = __float_as_uint(f);
    return (u & 0x80000000u) ? ~u : (u | 0x80000000u);
}

// MFMA-fragment global order:
// dst[wave*512 + lane*8 + j] <-> src[row=(wave>>6)*128+(wave&7)*16+(lane&15)]
//                                   [k=((wave>>3)&7)*32+(lane>>4)*8+j]
static __device__ __forceinline__ void load_row8(const float* __restrict__ src,
                                                 int wave_id, int lane,
                                                 float* vv, size_t* o) {
    int rb = wave_id >> 6, kc = (wave_id >> 3) & 7, t = wave_id & 7;
    int row = rb * 128 + t * 16 + (lane & 15);
    int k   = kc * 32 + (lane >> 4) * 8;
    const float* s = &src[row * DIM + k];
    float4 v0 = *(const float4*)s, v1 = *(const float4*)(s + 4);
    vv[0]=v0.x; vv[1]=v0.y; vv[2]=v0.z; vv[3]=v0.w;
    vv[4]=v1.x; vv[5]=v1.y; vv[6]=v1.z; vv[7]=v1.w;
    *o = (size_t)wave_id * 512 + lane * 8;
}
// fp16 pack (RN-even via native conversion). scale is an exact power of two:
// e is pre-scaled by 1024 so all |e*1024|<=1.0 stay fp16-normal (no denorm
// flush risk in the matrix core); undone exactly in the fp32 epilogue.
static __device__ __forceinline__ void pack_wave_h16(const float* __restrict__ src,
                                                     u16* __restrict__ dst,
                                                     int wave_id, int lane,
                                                     float scale) {
    float vv[8]; size_t o;
    load_row8(src, wave_id, lane, vv, &o);
    h16x8 hv;
#pragma unroll
    for (int j = 0; j < 8; ++j) hv[j] = (_Float16)(vv[j] * scale);
    *(h16x8*)&dst[o] = hv;
}

// fused setup: pack x fp16 (blocks 0..4095), pack e fp16*1024 (+0..127),
// esq (+128..383), keys init (+384..511), counts zero (+512).
__global__ __launch_bounds__(256) void vq_setup(const float* __restrict__ x,
                                                const float* __restrict__ emb,
                                                u16* __restrict__ xh,
                                                u16* __restrict__ eh,
                                                float* __restrict__ esq,
                                                u64* __restrict__ keys,
                                                int* __restrict__ cnti) {
    const int b = blockIdx.x, tid = threadIdx.x;
    const int lane = tid & 63, w = tid >> 6;
    if (b < 4096) { pack_wave_h16(x, xh, b * 4 + w, lane, 1.0f); return; }
    const int p = b - 4096;
    if (p < 128) {
        pack_wave_h16(emb, eh, p * 4 + w, lane, 1024.0f);
    } else if (p < 384) {
        int c = (p - 128) * 4 + w;
        float4 v = *(const float4*)&emb[c * DIM + lane * 4];
        float s = v.x * v.x + v.y * v.y + v.z * v.z + v.w * v.w;
#pragma unroll
        for (int off = 32; off; off >>= 1) s += __shfl_xor(s, off, 64);
        if (lane == 0) esq[c] = s;
    } else if (p < 512) {
        keys[(p - 384) * 256 + tid] = ~0ULL;
    } else {
#pragma unroll
        for (int i = 0; i < 4; ++i) cnti[i * 256 + tid] = 0;
    }
}

// main MFMA scores+argmin: 2048 blocks; XCD swizzle (R4-proven: FETCH 132->20 MB).
// block = 128 rows x 128 cols, 4 waves 2x2, wave = 4x4 grid of 16x16x32.
// Single fp16 MFMA (R3-measured 148.9us total, best of 10 variants). dot error
// ~9e-6 sigma — better than the bf16 hi+lo pair it replaced. e pre-scaled by
// 2^10 (exact); dist = esq - acc/512 undoes it exactly.
// Schedule: 2-syncthreads single-buffer. The measured ledger pinning this:
// R1 counted-vmcnt pipeline -> 100us; R5 linear-pack glds-gather -> 43us;
// R6 zero-LDS reg loads -> 68us; R7 BK=64 -> neutral; R8 dbuf-prefetch ->
// neutral; R9 x-direct reg-staging -> 55us; R10 reg-argmin + 16KB LDS
// (8 blocks/CU) -> +10us. This exact configuration is the empirical optimum.
__global__ __launch_bounds__(256) void vq_scores_mfma(const u16* __restrict__ xh,
                                                      const u16* __restrict__ eh,
                                                      const float* __restrict__ esq,
                                                      u64* __restrict__ keys) {
    __shared__ __align__(16) char smem[33792];
    const int tid  = threadIdx.x;
    const int lane = tid & 63, w = tid >> 6;
    const int wm = w & 1, wn = w >> 1;
    const int raw = blockIdx.x;
    const int rb = (raw >> 6) * 8 + (raw & 7);
    const int cs = (raw >> 3) & 7;

    const u16* gb0 = xh + (size_t)rb * 32768;
    const u16* gb1 = eh + (size_t)cs * 32768;

    const h16x8* Ah = (const h16x8*)(smem);
    const h16x8* Bh = (const h16x8*)(smem + 8192);

    f32x4 acc[4][4];
#pragma unroll
    for (int i = 0; i < 4; ++i)
#pragma unroll
        for (int j = 0; j < 4; ++j) acc[i][j] = (f32x4)0.f;

    for (int kc = 0; kc < 8; ++kc) {
        __syncthreads();   // previous chunk's frag reads done before overwrite
        // 16 x 1KB wave-loads per chunk; wave w takes flat indices [4w, 4w+4)
#pragma unroll
        for (int j = 0; j < 4; ++j) {
            int t = w * 4 + j;
            int arr = t >> 3, slot = t & 7;
            const u16* g = (arr == 0 ? gb0 : gb1)
                           + kc * 4096 + slot * 512 + lane * 8;
            gl2lds16(g, smem + arr * 8192 + slot * 1024);
        }
        __syncthreads();   // drains vmcnt (incl. global_load_lds) + barrier

        h16x8 ah[4];
#pragma unroll
        for (int tm = 0; tm < 4; ++tm)
            ah[tm] = Ah[(wm * 4 + tm) * 64 + lane];
#pragma unroll
        for (int tn = 0; tn < 4; ++tn) {
            h16x8 bh = Bh[(wn * 4 + tn) * 64 + lane];
#pragma unroll
            for (int tm = 0; tm < 4; ++tm) {
                acc[tm][tn] = __builtin_amdgcn_mfma_f32_16x16x32_f16(ah[tm], bh, acc[tm][tn], 0, 0, 0);
            }
        }
    }

    // epilogue: dist = esq - 2*dot = esq - acc/512 (undo e*1024), per-row argmin.
    // C/D layout: col = lane&15, row = (lane>>4)*4 + reg (m89/m91-verified)
    __syncthreads();
    float* cv = (float*)smem;            // [128 rows][33 slots] pad -> conflict-free
    int*   ci = (int*)(smem + 16896);
    const int ln = lane & 15, quad = lane >> 4;
#pragma unroll
    for (int tm = 0; tm < 4; ++tm) {
        float bv[4];
        int   bi[4];
#pragma unroll
        for (int r = 0; r < 4; ++r) { bv[r] = FLT_MAX; bi[r] = 0; }
#pragma unroll
        for (int tn = 0; tn < 4; ++tn) {          // ascending col -> lowest-idx ties
            int c = cs * 128 + wn * 64 + tn * 16 + ln;
            float ec = esq[c];
#pragma unroll
            for (int r = 0; r < 4; ++r) {
                float d = fmaf(-0.001953125f, acc[tm][tn][r], ec);
                if (d < bv[r]) { bv[r] = d; bi[r] = c; }
            }
        }
        int row0 = wm * 64 + tm * 16 + quad * 4;
        int slot = wn * 16 + ln;
#pragma unroll
        for (int r = 0; r < 4; ++r) {
            cv[(row0 + r) * 33 + slot] = bv[r];
            ci[(row0 + r) * 33 + slot] = bi[r];
        }
    }
    __syncthreads();
    if (tid < 128) {
        float bv = cv[tid * 33];
        int   bi = ci[tid * 33];
#pragma unroll
        for (int s = 1; s < 32; ++s) {
            float v = cv[tid * 33 + s];
            int  ix = ci[tid * 33 + s];
            if (v < bv || (v == bv && ix < bi)) { bv = v; bi = ix; }
        }
        u64 key = ((u64)fmap(bv) << 32) | (unsigned)bi;
        atomicMin(&keys[rb * 128 + tid], key);
    }
}

// streaming quantize + straight-through + loss partials + histogram + bi array.
// 2048 blocks x 16 rows; float4 throughout; one int atomic per row. (R4-proven)
__global__ __launch_bounds__(256) void vq_quant(const float* __restrict__ x,
                                                const float* __restrict__ emb,
                                                const u64* __restrict__ keys,
                                                float* __restrict__ outq,
                                                int* __restrict__ cnti,
                                                int* __restrict__ bi_arr,
                                                float* __restrict__ lpart) {
    const int tid = threadIdx.x, lane = tid & 63, w = tid >> 6;
    const float4* x4 = (const float4*)x;
    const float4* e4 = (const float4*)emb;
    float4* o4 = (float4*)outq;
    float lacc = 0.f;
#pragma unroll
    for (int it = 0; it < 4; ++it) {
        int row = blockIdx.x * 16 + it * 4 + w;
        int bi = (int)(unsigned)(keys[row] & 0xffffffffULL);
        if (lane == 0) { atomicAdd(&cnti[bi], 1); bi_arr[row] = bi; }
        float4 xv = x4[row * 64 + lane];
        float4 ev = e4[bi * 64 + lane];
        float4 q;
        q.x = xv.x + (ev.x - xv.x);  q.y = xv.y + (ev.y - xv.y);
        q.z = xv.z + (ev.z - xv.z);  q.w = xv.w + (ev.w - xv.w);
        o4[row * 64 + lane] = q;
        float dx = xv.x - ev.x, dy = xv.y - ev.y, dz = xv.z - ev.z, dwv = xv.w - ev.w;
        lacc += dx * dx + dy * dy + dz * dz + dwv * dwv;
    }
#pragma unroll
    for (int off = 32; off; off >>= 1) lacc += __shfl_xor(lacc, off, 64);
    __shared__ float red[4];
    if (lane == 0) red[w] = lacc;
    __syncthreads();
    if (tid == 0) lpart[blockIdx.x] = red[0] + red[1] + red[2] + red[3];
}

// mega-tail: grid 1024, one block per code m.
// int4 + unroll scan; n via the exact identity sum(counts) == N_TOK.
#define MEGA_CAP 6144
__global__ __launch_bounds__(256) void vq_mega(const float* __restrict__ x,
                                               const float* __restrict__ ema_count,
                                               const float* __restrict__ ema_weight,
                                               const int* __restrict__ cnti,
                                               const int* __restrict__ bi_arr,
                                               const float* __restrict__ lpart,
                                               float* __restrict__ out) {
    const int m = blockIdx.x, tid = threadIdx.x;
    __shared__ float fs[256];
    __shared__ int list[MEGA_CAP];
    __shared__ int lcount;

    float rsum = 0.f;
#pragma unroll
    for (int i = 0; i < 4; ++i) rsum += ema_count[tid * 4 + i];
    fs[tid] = rsum;
    if (tid == 0) lcount = 0;
    __syncthreads();
    for (int s = 128; s; s >>= 1) { if (tid < s) fs[tid] += fs[tid + s]; __syncthreads(); }
    const float n = DECAY_ * fs[0] + OMD_ * (float)N_TOK;
    __syncthreads();

    // scan bi_arr (int4, unrolled -> loads pipelined) for rows of code m
    const int4* b4 = (const int4*)bi_arr;
#pragma unroll 4
    for (int i = tid; i < N_TOK / 4; i += 256) {
        int4 v = b4[i];
        if (v.x == m) { int p = atomicAdd(&lcount, 1); if (p < MEGA_CAP) list[p] = 4 * i; }
        if (v.y == m) { int p = atomicAdd(&lcount, 1); if (p < MEGA_CAP) list[p] = 4 * i + 1; }
        if (v.z == m) { int p = atomicAdd(&lcount, 1); if (p < MEGA_CAP) list[p] = 4 * i + 2; }
        if (v.w == m) { int p = atomicAdd(&lcount, 1); if (p < MEGA_CAP) list[p] = 4 * i + 3; }
    }
    __syncthreads();
    const int nm = lcount;
    float dwsum;
    if (nm <= MEGA_CAP) {
        float a0 = 0.f, a1 = 0.f, a2 = 0.f, a3 = 0.f;
        int i = 0;
        for (; i + 4 <= nm; i += 4) {
            a0 += x[list[i]     * DIM + tid];
            a1 += x[list[i + 1] * DIM + tid];
            a2 += x[list[i + 2] * DIM + tid];
            a3 += x[list[i + 3] * DIM + tid];
        }
        for (; i < nm; ++i) a0 += x[list[i] * DIM + tid];
        dwsum = (a0 + a1) + (a2 + a3);
    } else {
        // defensive fallback (not expected with this data distribution)
        __shared__ int chunk[256];
        float a0 = 0.f;
        for (int base = 0; base < N_TOK; base += 256) {
            __syncthreads();
            chunk[tid] = bi_arr[base + tid];
            __syncthreads();
            for (int j = 0; j < 256; ++j)
                if (chunk[j] == m) a0 += x[(base + j) * DIM + tid];
        }
        dwsum = a0;
    }

    float raw_m = DECAY_ * ema_count[m] + OMD_ * (float)nm;
    float ncm = (raw_m + EPS_) / (n + MEPS_) * n;
    float nw = DECAY_ * ema_weight[m * DIM + tid] + OMD_ * dwsum;
    out[OUT_NW + m * DIM + tid] = nw;
    out[OUT_NE + m * DIM + tid] = nw / ncm;
    if (tid == 0) out[OUT_NC + m] = ncm;

    if (m == 0) {
        float ent = 0.f;
#pragma unroll
        for (int i = 0; i < 4; ++i) {
            float p = (float)cnti[tid * 4 + i] / (float)N_TOK;
            ent += p * logf(p + 1e-10f);
        }
        __syncthreads();
        fs[tid] = ent;
        __syncthreads();
        for (int s = 128; s; s >>= 1) { if (tid < s) fs[tid] += fs[tid + s]; __syncthreads(); }
        float entr = fs[0];
        __syncthreads();
        float ls = 0.f;
#pragma unroll
        for (int k = 0; k < 8; ++k) ls += lpart[tid + 256 * k];
        fs[tid] = ls;
        __syncthreads();
        for (int s = 128; s; s >>= 1) { if (tid < s) fs[tid] += fs[tid + s]; __syncthreads(); }
        if (tid == 0) {
            float mean = fs[0] / (float)(N_TOK * DIM);
            out[OUT_COMMIT]   = 0.25f * mean;
            out[OUT_CODEBOOK] = mean;
            out[OUT_PERP]     = expf(-entr);
        }
    }
}

extern "C" void kernel_launch(void* const* d_in, const int* in_sizes, int n_in,
                              void* d_out, int out_size, void* d_ws, size_t ws_size,
                              hipStream_t stream) {
    const float* x          = (const float*)d_in[0];
    const float* emb        = (const float*)d_in[1];
    const float* ema_count  = (const float*)d_in[2];
    const float* ema_weight = (const float*)d_in[3];
    float* out = (float*)d_out;
    float* wf  = (float*)d_ws;

    // xh lives in the d_out quantized region (16.8 of 33.5 MB); vq_quant
    // overwrites it afterwards.
    u16* xh = (u16*)d_out;
    u16* eh = (u16*)(wf + WS_EH);

    float* esq    = wf + WS_ESQ;
    int*   cnti   = (int*)(wf + WS_CNTI);
    int*   bi_arr = (int*)(wf + WS_BI);
    float* lpart  = wf + WS_LP;
    u64*   keys   = (u64*)(wf + WS_KEY);

    vq_setup<<<4609, 256, 0, stream>>>(x, emb, xh, eh, esq, keys, cnti);
    vq_scores_mfma<<<2048, 256, 0, stream>>>(xh, eh, esq, keys);
    vq_quant<<<2048, 256, 0, stream>>>(x, emb, keys, out, cnti, bi_arr, lpart);
    vq_mega<<<MCODE, 256, 0, stream>>>(x, ema_count, ema_weight, cnti, bi_arr,
                                       lpart, out);
}